// Round 3
// baseline (521.384 us; speedup 1.0000x reference)
//
#include <hip/hip_runtime.h>
#include <hip/hip_bf16.h>
#include <stdint.h>

// Problem constants (from reference setup_inputs)
#define M_DIM   32768        // B*S = 32*1024
#define IN_DIM  1152
#define OUT_DIM 1152
#define R_DIM   64
#define QMAXF   255.0f

#define RED_BLOCKS 2048

typedef float  f32x4  __attribute__((ext_vector_type(4)));
typedef __bf16 bf16x8 __attribute__((ext_vector_type(8)));

// RNE float -> bf16 bits (finite inputs only)
static __device__ __forceinline__ unsigned short f2bf(float f) {
    unsigned int u = __float_as_uint(f);
    unsigned int r = (u + 0x7fffu + ((u >> 16) & 1u)) >> 16;
    return (unsigned short)r;
}

// ---------------- Pass 0: fold low-rank into weight (bf16) + rs + counter reset --
// Wc[o][i] = quant_w[o][i] + sum_r left_w[o][r] * right_w[r][i];  rs[c] = 1/scales[c]
__global__ __launch_bounds__(256) void k_wprep(const float* __restrict__ qw,
                                               const float* __restrict__ rw,
                                               const float* __restrict__ lw,
                                               const float* __restrict__ scales,
                                               unsigned short* __restrict__ wc,
                                               float* __restrict__ rs,
                                               unsigned int* __restrict__ cnt) {
    int idx = blockIdx.x * 256 + threadIdx.x;   // over OUT*IN, exact grid
    if (idx == 0) *cnt = 0u;                    // reset last-block counter (stream-ordered before k_minmax)
    if (idx < IN_DIM) rs[idx] = 1.0f / scales[idx];
    int o = idx / IN_DIM;
    int i = idx - o * IN_DIM;
    float acc = qw[idx];
    #pragma unroll 8
    for (int r = 0; r < R_DIM; r++)
        acc += lw[o * R_DIM + r] * rw[r * IN_DIM + i];
    wc[idx] = f2bf(acc);
}

// ---------------- Pass 1: global min/max of x*rs, fused finalize (last block) ----
__global__ __launch_bounds__(256) void k_minmax(const float* __restrict__ x,
                                                const float* __restrict__ rs,
                                                const float* __restrict__ scales,
                                                float* __restrict__ partials,
                                                float* __restrict__ qp,
                                                float* __restrict__ comb,
                                                unsigned int* __restrict__ cnt) {
    const int n4 = (M_DIM * IN_DIM) / 4;      // 9,437,184 float4s; 2048*256*18 exactly
    int tid = blockIdx.x * 256 + threadIdx.x;
    const int stride = RED_BLOCKS * 256;
    float mn = 3.4e38f, mx = -3.4e38f;
    for (int i4 = tid; i4 < n4; i4 += stride) {
        int i = i4 * 4;
        float4 xv = *(const float4*)(x + i);
        int c = i % IN_DIM;                   // IN_DIM % 4 == 0 -> aligned
        float4 sv = *(const float4*)(rs + c);
        float a0 = xv.x * sv.x, a1 = xv.y * sv.y;
        float a2 = xv.z * sv.z, a3 = xv.w * sv.w;
        mn = fminf(mn, fminf(fminf(a0, a1), fminf(a2, a3)));
        mx = fmaxf(mx, fmaxf(fmaxf(a0, a1), fmaxf(a2, a3)));
    }
    #pragma unroll
    for (int off = 32; off > 0; off >>= 1) {
        mn = fminf(mn, __shfl_down(mn, off));
        mx = fmaxf(mx, __shfl_down(mx, off));
    }
    __shared__ float smn[4], smx[4];
    __shared__ int sLast;
    __shared__ float s_qs;
    int lane = threadIdx.x & 63, wv = threadIdx.x >> 6;
    if (lane == 0) { smn[wv] = mn; smx[wv] = mx; }
    __syncthreads();
    if (threadIdx.x == 0) {
        float bmn = fminf(fminf(smn[0], smn[1]), fminf(smn[2], smn[3]));
        float bmx = fmaxf(fmaxf(smx[0], smx[1]), fmaxf(smx[2], smx[3]));
        // agent-scope atomic stores: visible to the (possibly cross-XCD) last block
        __hip_atomic_store(&partials[blockIdx.x * 2],     bmn,
                           __ATOMIC_RELAXED, __HIP_MEMORY_SCOPE_AGENT);
        __hip_atomic_store(&partials[blockIdx.x * 2 + 1], bmx,
                           __ATOMIC_RELAXED, __HIP_MEMORY_SCOPE_AGENT);
        unsigned int prev = __hip_atomic_fetch_add(cnt, 1u,
                           __ATOMIC_ACQ_REL, __HIP_MEMORY_SCOPE_AGENT);
        sLast = (prev == (unsigned int)(RED_BLOCKS - 1));
    }
    __syncthreads();                          // sLast valid; block-uniform branch below
    if (sLast) {
        float fmn = 3.4e38f, fmx = -3.4e38f;
        for (int i = threadIdx.x; i < RED_BLOCKS; i += 256) {
            float a = __hip_atomic_load(&partials[i * 2],
                       __ATOMIC_ACQUIRE, __HIP_MEMORY_SCOPE_AGENT);
            float b = __hip_atomic_load(&partials[i * 2 + 1],
                       __ATOMIC_ACQUIRE, __HIP_MEMORY_SCOPE_AGENT);
            fmn = fminf(fmn, a);
            fmx = fmaxf(fmx, b);
        }
        #pragma unroll
        for (int off = 32; off > 0; off >>= 1) {
            fmn = fminf(fmn, __shfl_down(fmn, off));
            fmx = fmaxf(fmx, __shfl_down(fmx, off));
        }
        if (lane == 0) { smn[wv] = fmn; smx[wv] = fmx; }
        __syncthreads();
        if (threadIdx.x == 0) {
            float bmn = fminf(fminf(smn[0], smn[1]), fminf(smn[2], smn[3]));
            float bmx = fmaxf(fmaxf(smx[0], smx[1]), fmaxf(smx[2], smx[3]));
            float qs = (bmx - bmn) / QMAXF;
            float zp = rintf(-bmn / qs);
            qp[0] = qs;
            qp[1] = zp;
            qp[2] = -zp;            // clamp lo for (q - zp)
            qp[3] = QMAXF - zp;     // clamp hi for (q - zp)
            s_qs = qs;
        }
        __syncthreads();
        float qs = s_qs;
        for (int c = threadIdx.x; c < IN_DIM; c += 256)
            comb[c] = 1.0f / (scales[c] * qs);   // x*comb == (x/scales)/qs (to ~2 ulp)
    }
}

// ---------------- Pass 2: GEMM with fused on-the-fly quantization ----------------
// C = qs * (Aq @ Wc^T) + bias, where Aq = clamp(rint(x*comb), -zp, 255-zp) in bf16.
// x: [M][K] fp32, Wc: [N][K] bf16, C: [M][N] fp32
#define BM 128
#define BN 128
#define BK 32

__global__ __launch_bounds__(256) void k_gemm_fq(const float* __restrict__ x,
                                                 const unsigned short* __restrict__ Bw,
                                                 const float* __restrict__ bias,
                                                 const float* __restrict__ qp,
                                                 const float* __restrict__ comb,
                                                 float* __restrict__ C) {
    __shared__ __align__(16) unsigned short As[BM * BK];   // 8 KB bf16 (quantized A)
    __shared__ __align__(16) unsigned short Bs[BN * BK];   // 8 KB
    const int tid = threadIdx.x;
    // XCD-aware remap: 2304 blocks, 8 XCDs (round-robin by linear id).
    // Within an XCD the 9 bn-blocks of one bm are consecutive -> co-resident,
    // so each x panel (590 KB fp32) is HBM-fetched once per XCD, L2-hit 8x.
    const int lid = blockIdx.x;
    const int xcd = lid & 7;
    const int kk  = lid >> 3;            // 0..287
    const int bml = kk / 9;              // 0..31
    const int bn  = kk - bml * 9;        // 0..8
    const int bm  = xcd * 32 + bml;      // 0..255
    const int K = IN_DIM, N = OUT_DIM;

    const float lo = qp[2], hi = qp[3];

    // A staging (reg-quantize): thread t owns row t>>1, col-block (t&1)*16 (16 floats).
    const int ar = tid >> 1;
    const int ac = (tid & 1) * 16;
    const float* gx = x + (size_t)(bm * BM + ar) * K + ac;
    unsigned short* lA = As + ar * BK + ac;          // byte off = ar*64 + ac*2: 16B aligned

    // B staging via global_load_lds (16B/lane, wave-uniform base + lane*16).
    const int r0 = tid >> 2;
    const int c0 = (tid & 3) * 8;
    const unsigned short* gb0 = Bw + (size_t)(bn * BN + r0) * K + c0;
    const unsigned short* gb1 = gb0 + (size_t)64 * K;
    unsigned short* lB0 = Bs + tid * 8;
    unsigned short* lB1 = Bs + tid * 8 + 2048;

    f32x4 acc[4][4];
    #pragma unroll
    for (int mi = 0; mi < 4; mi++)
        #pragma unroll
        for (int ni = 0; ni < 4; ni++)
            acc[mi][ni] = (f32x4)0.0f;

    const int lane = tid & 63, wv = tid >> 6;
    const int wm = (wv & 1) * 64;          // wave m-origin within block tile
    const int wn = (wv >> 1) * 64;         // wave n-origin
    const int l16 = lane & 15, l4 = lane >> 4;
    const bf16x8* Asv = (const bf16x8*)As; // row stride = 4 (in 16B units)
    const bf16x8* Bsv = (const bf16x8*)Bs;
    const int afo = (wm + l16) * 4 + l4;   // A[m=lane&15][k=(lane>>4)*8+j]
    const int bfo = (wn + l16) * 4 + l4;   // B[k][n=lane&15] from Wc[n][k]

    for (int k0 = 0; k0 < K; k0 += BK) {
        // B tile: fire-and-forget direct-to-LDS
        __builtin_amdgcn_global_load_lds(
            (const __attribute__((address_space(1))) unsigned int*)(gb0 + k0),
            (__attribute__((address_space(3))) unsigned int*)lB0, 16, 0, 0);
        __builtin_amdgcn_global_load_lds(
            (const __attribute__((address_space(1))) unsigned int*)(gb1 + k0),
            (__attribute__((address_space(3))) unsigned int*)lB1, 16, 0, 0);
        // A tile: load 16 fp32, quantize to (q - zp) bf16 (exact integers), ds_write
        const float* gxk = gx + k0;
        const float* cbk = comb + ac + k0;
        #pragma unroll
        for (int h = 0; h < 2; h++) {
            float4 v0 = *(const float4*)(gxk + h * 8);
            float4 v1 = *(const float4*)(gxk + h * 8 + 4);
            float4 u0 = *(const float4*)(cbk + h * 8);
            float4 u1 = *(const float4*)(cbk + h * 8 + 4);
            bf16x8 o;
            o[0] = (__bf16)fminf(fmaxf(rintf(v0.x * u0.x), lo), hi);
            o[1] = (__bf16)fminf(fmaxf(rintf(v0.y * u0.y), lo), hi);
            o[2] = (__bf16)fminf(fmaxf(rintf(v0.z * u0.z), lo), hi);
            o[3] = (__bf16)fminf(fmaxf(rintf(v0.w * u0.w), lo), hi);
            o[4] = (__bf16)fminf(fmaxf(rintf(v1.x * u1.x), lo), hi);
            o[5] = (__bf16)fminf(fmaxf(rintf(v1.y * u1.y), lo), hi);
            o[6] = (__bf16)fminf(fmaxf(rintf(v1.z * u1.z), lo), hi);
            o[7] = (__bf16)fminf(fmaxf(rintf(v1.w * u1.w), lo), hi);
            *((bf16x8*)lA + h) = o;
        }
        __syncthreads();                   // drains vmcnt (B) + lgkmcnt (A writes)

        bf16x8 af[4], bf[4];
        #pragma unroll
        for (int mi = 0; mi < 4; mi++) af[mi] = Asv[afo + mi * 64];
        #pragma unroll
        for (int ni = 0; ni < 4; ni++) bf[ni] = Bsv[bfo + ni * 64];
        #pragma unroll
        for (int mi = 0; mi < 4; mi++)
            #pragma unroll
            for (int ni = 0; ni < 4; ni++)
                acc[mi][ni] = __builtin_amdgcn_mfma_f32_16x16x32_bf16(
                    af[mi], bf[ni], acc[mi][ni], 0, 0, 0);
        __syncthreads();                   // LDS reads done before next overwrite
    }

    const float qs = qp[0];
    #pragma unroll
    for (int mi = 0; mi < 4; mi++) {
        int row0 = bm * BM + wm + mi * 16 + l4 * 4;
        #pragma unroll
        for (int ni = 0; ni < 4; ni++) {
            int col = bn * BN + wn + ni * 16 + l16;
            float bv = bias[col];
            #pragma unroll
            for (int r = 0; r < 4; r++)
                C[(size_t)(row0 + r) * N + col] = acc[mi][ni][r] * qs + bv;
        }
    }
}

extern "C" void kernel_launch(void* const* d_in, const int* in_sizes, int n_in,
                              void* d_out, int out_size, void* d_ws, size_t ws_size,
                              hipStream_t stream) {
    const float* x      = (const float*)d_in[0];
    const float* qw     = (const float*)d_in[1];
    const float* rw     = (const float*)d_in[2];
    const float* lw     = (const float*)d_in[3];
    const float* bias   = (const float*)d_in[4];
    const float* scales = (const float*)d_in[5];

    char* ws = (char*)d_ws;
    // Workspace layout (16B aligned), ~2.7 MiB total
    unsigned short* wc = (unsigned short*)ws;                     // 2,654,208 B
    float* partials    = (float*)(ws + 2654208);                  //    16,384 B
    float* qp          = (float*)(ws + 2654208 + 16384);          //        64 B
    float* rs          = (float*)(ws + 2654208 + 16384 + 64);     //     4,608 B
    float* comb        = (float*)(ws + 2654208 + 16384 + 64 + 4608);          // 4,608 B
    unsigned int* cnt  = (unsigned int*)(ws + 2654208 + 16384 + 64 + 4608 + 4608); // 64 B

    k_wprep <<<(OUT_DIM * IN_DIM) / 256, 256, 0, stream>>>(qw, rw, lw, scales, wc, rs, cnt);
    k_minmax<<<RED_BLOCKS, 256, 0, stream>>>(x, rs, scales, partials, qp, comb, cnt);
    k_gemm_fq<<<2304, 256, 0, stream>>>(x, wc, bias, qp, comb, (float*)d_out);
}

// Round 4
// 462.324 us; speedup vs baseline: 1.1277x; 1.1277x over previous
//
#include <hip/hip_runtime.h>
#include <hip/hip_bf16.h>
#include <stdint.h>

// Problem constants (from reference setup_inputs)
#define M_DIM   32768        // B*S = 32*1024
#define IN_DIM  1152
#define OUT_DIM 1152
#define R_DIM   64
#define QMAXF   255.0f

#define RED_BLOCKS 2048

typedef float  f32x4  __attribute__((ext_vector_type(4)));
typedef __bf16 bf16x8 __attribute__((ext_vector_type(8)));

// RNE float -> bf16 bits (finite inputs only)
static __device__ __forceinline__ unsigned short f2bf(float f) {
    unsigned int u = __float_as_uint(f);
    unsigned int r = (u + 0x7fffu + ((u >> 16) & 1u)) >> 16;
    return (unsigned short)r;
}

// ---------------- Pass 0: fold low-rank into weight (bf16) + reciprocal scales ----
// Wc[o][i] = quant_w[o][i] + sum_r left_w[o][r] * right_w[r][i];  rs[c] = 1/scales[c]
__global__ __launch_bounds__(256) void k_wprep(const float* __restrict__ qw,
                                               const float* __restrict__ rw,
                                               const float* __restrict__ lw,
                                               const float* __restrict__ scales,
                                               unsigned short* __restrict__ wc,
                                               float* __restrict__ rs) {
    int idx = blockIdx.x * 256 + threadIdx.x;   // over OUT*IN, exact grid
    if (idx < IN_DIM) rs[idx] = 1.0f / scales[idx];
    int o = idx / IN_DIM;
    int i = idx - o * IN_DIM;
    float acc = qw[idx];
    #pragma unroll 8
    for (int r = 0; r < R_DIM; r++)
        acc += lw[o * R_DIM + r] * rw[r * IN_DIM + i];
    wc[idx] = f2bf(acc);
}

// ---------------- Pass 1: global min/max of x * rs (plain two-level reduce) ------
__global__ __launch_bounds__(256) void k_minmax(const float* __restrict__ x,
                                                const float* __restrict__ rs,
                                                float* __restrict__ partials) {
    const int n4 = (M_DIM * IN_DIM) / 4;      // 9,437,184 float4s; 2048*256*18 exactly
    int tid = blockIdx.x * 256 + threadIdx.x;
    const int stride = RED_BLOCKS * 256;
    float mn = 3.4e38f, mx = -3.4e38f;
    for (int i4 = tid; i4 < n4; i4 += stride) {
        int i = i4 * 4;
        float4 xv = *(const float4*)(x + i);
        int c = i % IN_DIM;                   // IN_DIM % 4 == 0 -> aligned
        float4 sv = *(const float4*)(rs + c);
        float a0 = xv.x * sv.x, a1 = xv.y * sv.y;
        float a2 = xv.z * sv.z, a3 = xv.w * sv.w;
        mn = fminf(mn, fminf(fminf(a0, a1), fminf(a2, a3)));
        mx = fmaxf(mx, fmaxf(fmaxf(a0, a1), fmaxf(a2, a3)));
    }
    #pragma unroll
    for (int off = 32; off > 0; off >>= 1) {
        mn = fminf(mn, __shfl_down(mn, off));
        mx = fmaxf(mx, __shfl_down(mx, off));
    }
    __shared__ float smn[4], smx[4];
    int lane = threadIdx.x & 63, wv = threadIdx.x >> 6;
    if (lane == 0) { smn[wv] = mn; smx[wv] = mx; }
    __syncthreads();
    if (threadIdx.x == 0) {
        float bmn = fminf(fminf(smn[0], smn[1]), fminf(smn[2], smn[3]));
        float bmx = fmaxf(fmaxf(smx[0], smx[1]), fmaxf(smx[2], smx[3]));
        partials[blockIdx.x * 2]     = bmn;
        partials[blockIdx.x * 2 + 1] = bmx;
    }
}

// ---------------- Pass 2: finalize quant params + per-column combined recip -------
__global__ __launch_bounds__(256) void k_finalize(const float* __restrict__ partials,
                                                  const float* __restrict__ scales,
                                                  float* __restrict__ qp,
                                                  float* __restrict__ comb) {
    float mn = 3.4e38f, mx = -3.4e38f;
    for (int i = threadIdx.x; i < RED_BLOCKS; i += 256) {
        mn = fminf(mn, partials[i * 2]);
        mx = fmaxf(mx, partials[i * 2 + 1]);
    }
    #pragma unroll
    for (int off = 32; off > 0; off >>= 1) {
        mn = fminf(mn, __shfl_down(mn, off));
        mx = fmaxf(mx, __shfl_down(mx, off));
    }
    __shared__ float smn[4], smx[4];
    __shared__ float s_qs;
    int lane = threadIdx.x & 63, wv = threadIdx.x >> 6;
    if (lane == 0) { smn[wv] = mn; smx[wv] = mx; }
    __syncthreads();
    if (threadIdx.x == 0) {
        float bmn = fminf(fminf(smn[0], smn[1]), fminf(smn[2], smn[3]));
        float bmx = fmaxf(fmaxf(smx[0], smx[1]), fmaxf(smx[2], smx[3]));
        float qs = (bmx - bmn) / QMAXF;
        float zp = rintf(-bmn / qs);
        qp[0] = qs;
        qp[1] = zp;
        qp[2] = -zp;            // clamp lo for (q - zp)
        qp[3] = QMAXF - zp;     // clamp hi for (q - zp)
        s_qs = qs;
    }
    __syncthreads();
    float qs = s_qs;
    for (int c = threadIdx.x; c < IN_DIM; c += 256)
        comb[c] = 1.0f / (scales[c] * qs);   // x*comb == (x/scales)/qs (to ~2 ulp)
}

// ---------------- Pass 3: GEMM, fused on-the-fly quantization, 2-phase dbuf ------
// C = qs * (Aq @ Wc^T) + bias, where Aq = clamp(rint(x*comb), -zp, 255-zp) in bf16.
// x: [M][K] fp32, Wc: [N][K] bf16, C: [M][N] fp32
// Pipeline per tile t: {issue STAGE(t+1): B glds + A fp32 loads} -> ds_read/MFMA(t)
// -> quantize+ds_write(t+1) -> __syncthreads (vmcnt0+lgkm0+barrier). Stage latency
// of t+1 hides under MFMA(t). Double-buffered LDS; only compiler-managed waits.
#define BM 128
#define BN 128
#define BK 32
#define NT (IN_DIM / BK)      // 36 K-tiles

__global__ __launch_bounds__(256) void k_gemm_fq(const float* __restrict__ x,
                                                 const unsigned short* __restrict__ Bw,
                                                 const float* __restrict__ bias,
                                                 const float* __restrict__ qp,
                                                 const float* __restrict__ comb,
                                                 float* __restrict__ C) {
    __shared__ __align__(16) unsigned short As[2 * BM * BK];   // 2 x 8 KB (quantized A)
    __shared__ __align__(16) unsigned short Bs[2 * BN * BK];   // 2 x 8 KB
    const int tid = threadIdx.x;
    // XCD-aware remap: 2304 blocks, 8 XCDs (round-robin by linear id).
    const int lid = blockIdx.x;
    const int xcd = lid & 7;
    const int kk  = lid >> 3;            // 0..287
    const int bml = kk / 9;              // 0..31
    const int bn  = kk - bml * 9;        // 0..8
    const int bm  = xcd * 32 + bml;      // 0..255
    const int K = IN_DIM, N = OUT_DIM;

    const float lo = qp[2], hi = qp[3];

    // A staging: thread t owns row t>>1, col-block (t&1)*16 (16 fp32 -> 16 bf16).
    const int ar = tid >> 1;
    const int ac = (tid & 1) * 16;
    const float* gx = x + (size_t)(bm * BM + ar) * K + ac;

    // B staging via global_load_lds (16B/lane, wave-uniform base + lane*16).
    const int r0 = tid >> 2;
    const int c0 = (tid & 3) * 8;
    const unsigned short* gb0 = Bw + (size_t)(bn * BN + r0) * K + c0;
    const unsigned short* gb1 = gb0 + (size_t)64 * K;

    f32x4 acc[4][4];
    #pragma unroll
    for (int mi = 0; mi < 4; mi++)
        #pragma unroll
        for (int ni = 0; ni < 4; ni++)
            acc[mi][ni] = (f32x4)0.0f;

    const int lane = tid & 63, wv = tid >> 6;
    const int wm = (wv & 1) * 64;          // wave m-origin within block tile
    const int wn = (wv >> 1) * 64;         // wave n-origin
    const int l16 = lane & 15, l4 = lane >> 4;
    const int afo = (wm + l16) * 4 + l4;   // A[m][k] frag offset, 16B units in one buf
    const int bfo = (wn + l16) * 4 + l4;   // B[k][n] frag offset

    float4 xr0, xr1, xr2, xr3;             // in-flight A fp32 tile (16 floats)

    // ---- prologue: stage tile 0 into buffer 0 ----
    {
        __builtin_amdgcn_global_load_lds(
            (const __attribute__((address_space(1))) unsigned int*)gb0,
            (__attribute__((address_space(3))) unsigned int*)(Bs + tid * 8), 16, 0, 0);
        __builtin_amdgcn_global_load_lds(
            (const __attribute__((address_space(1))) unsigned int*)gb1,
            (__attribute__((address_space(3))) unsigned int*)(Bs + tid * 8 + 2048), 16, 0, 0);
        xr0 = *(const float4*)(gx + 0);
        xr1 = *(const float4*)(gx + 4);
        xr2 = *(const float4*)(gx + 8);
        xr3 = *(const float4*)(gx + 12);
        const float* cb = comb + ac;
        float4 u0 = *(const float4*)(cb + 0);
        float4 u1 = *(const float4*)(cb + 4);
        float4 u2 = *(const float4*)(cb + 8);
        float4 u3 = *(const float4*)(cb + 12);
        bf16x8 o0, o1;
        o0[0] = (__bf16)fminf(fmaxf(rintf(xr0.x * u0.x), lo), hi);
        o0[1] = (__bf16)fminf(fmaxf(rintf(xr0.y * u0.y), lo), hi);
        o0[2] = (__bf16)fminf(fmaxf(rintf(xr0.z * u0.z), lo), hi);
        o0[3] = (__bf16)fminf(fmaxf(rintf(xr0.w * u0.w), lo), hi);
        o0[4] = (__bf16)fminf(fmaxf(rintf(xr1.x * u1.x), lo), hi);
        o0[5] = (__bf16)fminf(fmaxf(rintf(xr1.y * u1.y), lo), hi);
        o0[6] = (__bf16)fminf(fmaxf(rintf(xr1.z * u1.z), lo), hi);
        o0[7] = (__bf16)fminf(fmaxf(rintf(xr1.w * u1.w), lo), hi);
        o1[0] = (__bf16)fminf(fmaxf(rintf(xr2.x * u2.x), lo), hi);
        o1[1] = (__bf16)fminf(fmaxf(rintf(xr2.y * u2.y), lo), hi);
        o1[2] = (__bf16)fminf(fmaxf(rintf(xr2.z * u2.z), lo), hi);
        o1[3] = (__bf16)fminf(fmaxf(rintf(xr2.w * u2.w), lo), hi);
        o1[4] = (__bf16)fminf(fmaxf(rintf(xr3.x * u3.x), lo), hi);
        o1[5] = (__bf16)fminf(fmaxf(rintf(xr3.y * u3.y), lo), hi);
        o1[6] = (__bf16)fminf(fmaxf(rintf(xr3.z * u3.z), lo), hi);
        o1[7] = (__bf16)fminf(fmaxf(rintf(xr3.w * u3.w), lo), hi);
        bf16x8* dst = (bf16x8*)(As + ar * BK + ac);
        dst[0] = o0;
        dst[1] = o1;
    }
    __syncthreads();

    for (int t = 0; t < NT; ++t) {
        const int cur = t & 1;
        const int nxt = cur ^ 1;
        const bool more = (t + 1) < NT;

        // ---- STAGE(t+1): issue loads early, consume late ----
        if (more) {
            const int kc = (t + 1) * BK;
            __builtin_amdgcn_global_load_lds(
                (const __attribute__((address_space(1))) unsigned int*)(gb0 + kc),
                (__attribute__((address_space(3))) unsigned int*)(Bs + nxt * 4096 + tid * 8),
                16, 0, 0);
            __builtin_amdgcn_global_load_lds(
                (const __attribute__((address_space(1))) unsigned int*)(gb1 + kc),
                (__attribute__((address_space(3))) unsigned int*)(Bs + nxt * 4096 + tid * 8 + 2048),
                16, 0, 0);
            const float* gxk = gx + kc;
            xr0 = *(const float4*)(gxk + 0);
            xr1 = *(const float4*)(gxk + 4);
            xr2 = *(const float4*)(gxk + 8);
            xr3 = *(const float4*)(gxk + 12);
        }

        // ---- compute tile t from buffer cur ----
        const bf16x8* Asv = (const bf16x8*)(As + cur * 4096);
        const bf16x8* Bsv = (const bf16x8*)(Bs + cur * 4096);
        bf16x8 af[4], bf[4];
        #pragma unroll
        for (int mi = 0; mi < 4; mi++) af[mi] = Asv[afo + mi * 64];
        #pragma unroll
        for (int ni = 0; ni < 4; ni++) bf[ni] = Bsv[bfo + ni * 64];
        #pragma unroll
        for (int mi = 0; mi < 4; mi++)
            #pragma unroll
            for (int ni = 0; ni < 4; ni++)
                acc[mi][ni] = __builtin_amdgcn_mfma_f32_16x16x32_bf16(
                    af[mi], bf[ni], acc[mi][ni], 0, 0, 0);

        // ---- quantize A(t+1) from regs, write to buffer nxt ----
        if (more) {
            const float* cb = comb + ac + (t + 1) * BK;
            float4 u0 = *(const float4*)(cb + 0);
            float4 u1 = *(const float4*)(cb + 4);
            float4 u2 = *(const float4*)(cb + 8);
            float4 u3 = *(const float4*)(cb + 12);
            bf16x8 o0, o1;
            o0[0] = (__bf16)fminf(fmaxf(rintf(xr0.x * u0.x), lo), hi);
            o0[1] = (__bf16)fminf(fmaxf(rintf(xr0.y * u0.y), lo), hi);
            o0[2] = (__bf16)fminf(fmaxf(rintf(xr0.z * u0.z), lo), hi);
            o0[3] = (__bf16)fminf(fmaxf(rintf(xr0.w * u0.w), lo), hi);
            o0[4] = (__bf16)fminf(fmaxf(rintf(xr1.x * u1.x), lo), hi);
            o0[5] = (__bf16)fminf(fmaxf(rintf(xr1.y * u1.y), lo), hi);
            o0[6] = (__bf16)fminf(fmaxf(rintf(xr1.z * u1.z), lo), hi);
            o0[7] = (__bf16)fminf(fmaxf(rintf(xr1.w * u1.w), lo), hi);
            o1[0] = (__bf16)fminf(fmaxf(rintf(xr2.x * u2.x), lo), hi);
            o1[1] = (__bf16)fminf(fmaxf(rintf(xr2.y * u2.y), lo), hi);
            o1[2] = (__bf16)fminf(fmaxf(rintf(xr2.z * u2.z), lo), hi);
            o1[3] = (__bf16)fminf(fmaxf(rintf(xr2.w * u2.w), lo), hi);
            o1[4] = (__bf16)fminf(fmaxf(rintf(xr3.x * u3.x), lo), hi);
            o1[5] = (__bf16)fminf(fmaxf(rintf(xr3.y * u3.y), lo), hi);
            o1[6] = (__bf16)fminf(fmaxf(rintf(xr3.z * u3.z), lo), hi);
            o1[7] = (__bf16)fminf(fmaxf(rintf(xr3.w * u3.w), lo), hi);
            bf16x8* dst = (bf16x8*)(As + nxt * 4096 + ar * BK + ac);
            dst[0] = o0;
            dst[1] = o1;
        }

        __syncthreads();   // vmcnt(0)+lgkmcnt(0)+barrier: buffers for t+1 ready
    }

    const float qs = qp[0];
    #pragma unroll
    for (int mi = 0; mi < 4; mi++) {
        int row0 = bm * BM + wm + mi * 16 + l4 * 4;
        #pragma unroll
        for (int ni = 0; ni < 4; ni++) {
            int col = bn * BN + wn + ni * 16 + l16;
            float bv = bias[col];
            #pragma unroll
            for (int r = 0; r < 4; r++)
                C[(size_t)(row0 + r) * N + col] = acc[mi][ni][r] * qs + bv;
        }
    }
}

extern "C" void kernel_launch(void* const* d_in, const int* in_sizes, int n_in,
                              void* d_out, int out_size, void* d_ws, size_t ws_size,
                              hipStream_t stream) {
    const float* x      = (const float*)d_in[0];
    const float* qw     = (const float*)d_in[1];
    const float* rw     = (const float*)d_in[2];
    const float* lw     = (const float*)d_in[3];
    const float* bias   = (const float*)d_in[4];
    const float* scales = (const float*)d_in[5];

    char* ws = (char*)d_ws;
    // Workspace layout (16B aligned), ~2.7 MiB total
    unsigned short* wc = (unsigned short*)ws;                     // 2,654,208 B
    float* partials    = (float*)(ws + 2654208);                  //    16,384 B
    float* qp          = (float*)(ws + 2654208 + 16384);          //        64 B
    float* rs          = (float*)(ws + 2654208 + 16384 + 64);     //     4,608 B
    float* comb        = (float*)(ws + 2654208 + 16384 + 64 + 4608);   // 4,608 B

    k_wprep   <<<(OUT_DIM * IN_DIM) / 256, 256, 0, stream>>>(qw, rw, lw, scales, wc, rs);
    k_minmax  <<<RED_BLOCKS, 256, 0, stream>>>(x, rs, partials);
    k_finalize<<<1,          256, 0, stream>>>(partials, scales, qp, comb);

    k_gemm_fq<<<2304, 256, 0, stream>>>(x, wc, bias, qp, comb, (float*)d_out);
}

// Round 5
// 438.134 us; speedup vs baseline: 1.1900x; 1.0552x over previous
//
#include <hip/hip_runtime.h>
#include <hip/hip_bf16.h>
#include <stdint.h>

// Problem constants (from reference setup_inputs)
#define M_DIM   32768        // B*S = 32*1024
#define IN_DIM  1152
#define OUT_DIM 1152
#define R_DIM   64
#define QMAXF   255.0f

#define RED_BLOCKS 2048
#define QBLOCKS    4096

typedef float  f32x4  __attribute__((ext_vector_type(4)));
typedef __bf16 bf16x8 __attribute__((ext_vector_type(8)));

// RNE float -> bf16 bits (finite inputs only)
static __device__ __forceinline__ unsigned short f2bf(float f) {
    unsigned int u = __float_as_uint(f);
    unsigned int r = (u + 0x7fffu + ((u >> 16) & 1u)) >> 16;
    return (unsigned short)r;
}

// ---------------- Pass 0: fold low-rank into weight (bf16) + reciprocal scales ----
// Wc[o][i] = quant_w[o][i] + sum_r left_w[o][r] * right_w[r][i];  rs[c] = 1/scales[c]
__global__ __launch_bounds__(256) void k_wprep(const float* __restrict__ qw,
                                               const float* __restrict__ rw,
                                               const float* __restrict__ lw,
                                               const float* __restrict__ scales,
                                               unsigned short* __restrict__ wc,
                                               float* __restrict__ rs) {
    int idx = blockIdx.x * 256 + threadIdx.x;   // over OUT*IN, exact grid
    if (idx < IN_DIM) rs[idx] = 1.0f / scales[idx];
    int o = idx / IN_DIM;
    int i = idx - o * IN_DIM;
    float acc = qw[idx];
    #pragma unroll 8
    for (int r = 0; r < R_DIM; r++)
        acc += lw[o * R_DIM + r] * rw[r * IN_DIM + i];
    wc[idx] = f2bf(acc);
}

// ---------------- Pass 1: global min/max of x * rs ------------------------------
__global__ __launch_bounds__(256) void k_minmax(const float* __restrict__ x,
                                                const float* __restrict__ rs,
                                                float* __restrict__ partials) {
    const int n4 = (M_DIM * IN_DIM) / 4;      // 9,437,184 float4s
    int tid = blockIdx.x * 256 + threadIdx.x;
    const int stride = RED_BLOCKS * 256;
    float mn = 3.4e38f, mx = -3.4e38f;
    for (int i4 = tid; i4 < n4; i4 += stride) {
        int i = i4 * 4;
        float4 xv = *(const float4*)(x + i);
        int c = i % IN_DIM;                   // IN_DIM % 4 == 0 -> aligned
        float4 sv = *(const float4*)(rs + c);
        float a0 = xv.x * sv.x, a1 = xv.y * sv.y;
        float a2 = xv.z * sv.z, a3 = xv.w * sv.w;
        mn = fminf(mn, fminf(fminf(a0, a1), fminf(a2, a3)));
        mx = fmaxf(mx, fmaxf(fmaxf(a0, a1), fmaxf(a2, a3)));
    }
    #pragma unroll
    for (int off = 32; off > 0; off >>= 1) {
        mn = fminf(mn, __shfl_down(mn, off));
        mx = fmaxf(mx, __shfl_down(mx, off));
    }
    __shared__ float smn[4], smx[4];
    int lane = threadIdx.x & 63, wv = threadIdx.x >> 6;
    if (lane == 0) { smn[wv] = mn; smx[wv] = mx; }
    __syncthreads();
    if (threadIdx.x == 0) {
        float bmn = fminf(fminf(smn[0], smn[1]), fminf(smn[2], smn[3]));
        float bmx = fmaxf(fmaxf(smx[0], smx[1]), fmaxf(smx[2], smx[3]));
        partials[blockIdx.x * 2]     = bmn;
        partials[blockIdx.x * 2 + 1] = bmx;
    }
}

// ---------------- Pass 2: finalize quant params + per-column combined recip -------
__global__ __launch_bounds__(256) void k_finalize(const float* __restrict__ partials,
                                                  const float* __restrict__ scales,
                                                  float* __restrict__ qp,
                                                  float* __restrict__ comb) {
    float mn = 3.4e38f, mx = -3.4e38f;
    for (int i = threadIdx.x; i < RED_BLOCKS; i += 256) {
        mn = fminf(mn, partials[i * 2]);
        mx = fmaxf(mx, partials[i * 2 + 1]);
    }
    #pragma unroll
    for (int off = 32; off > 0; off >>= 1) {
        mn = fminf(mn, __shfl_down(mn, off));
        mx = fmaxf(mx, __shfl_down(mx, off));
    }
    __shared__ float smn[4], smx[4];
    __shared__ float s_qs;
    int lane = threadIdx.x & 63, wv = threadIdx.x >> 6;
    if (lane == 0) { smn[wv] = mn; smx[wv] = mx; }
    __syncthreads();
    if (threadIdx.x == 0) {
        float bmn = fminf(fminf(smn[0], smn[1]), fminf(smn[2], smn[3]));
        float bmx = fmaxf(fmaxf(smx[0], smx[1]), fmaxf(smx[2], smx[3]));
        float qs = (bmx - bmn) / QMAXF;
        float zp = rintf(-bmn / qs);
        qp[0] = qs;
        qp[1] = zp;
        qp[2] = -zp;            // clamp lo for (q - zp)
        qp[3] = QMAXF - zp;     // clamp hi for (q - zp)
        s_qs = qs;
    }
    __syncthreads();
    float qs = s_qs;
    for (int c = threadIdx.x; c < IN_DIM; c += 256)
        comb[c] = 1.0f / (scales[c] * qs);   // x*comb == (x/scales)/qs (to ~2 ulp)
}

// ---------------- Pass 3: quantize, store (q - zp) as exact bf16 -----------------
// q - zp = clamp(rint(x*comb), -zp, 255-zp)   (zp integral -> clamp shift is exact)
__global__ __launch_bounds__(256) void k_quant(const float* __restrict__ x,
                                               const float* __restrict__ comb,
                                               const float* __restrict__ qp,
                                               unsigned short* __restrict__ xq) {
    const float lo = qp[2], hi = qp[3];
    const int n4 = (M_DIM * IN_DIM) / 4;
    int tid = blockIdx.x * 256 + threadIdx.x;
    const int stride = QBLOCKS * 256;
    for (int i4 = tid; i4 < n4; i4 += stride) {
        int i = i4 * 4;
        float4 xv = *(const float4*)(x + i);
        int c = i % IN_DIM;
        float4 cb = *(const float4*)(comb + c);
        float a[4] = { xv.x * cb.x, xv.y * cb.y, xv.z * cb.z, xv.w * cb.w };
        ushort4 o;
        unsigned short* op = (unsigned short*)&o;
        #pragma unroll
        for (int j = 0; j < 4; j++) {
            float q = rintf(a[j]);
            q = fminf(fmaxf(q, lo), hi);
            op[j] = f2bf(q);                  // integer in [-255,255]: exact in bf16
        }
        *(ushort4*)(xq + i) = o;
    }
}

// ---------------- Pass 4: GEMM  C = qs * (A @ Wc^T) + bias -----------------------
// A: [M][K] bf16 (q - zp), Wc: [N][K] bf16, C: [M][N] fp32
// 2-phase double-buffered: STAGE(t+1) issued BEFORE compute(t); ONE __syncthreads
// per iter (its vmcnt(0) covers stage completion; its barrier orders buf[cur]
// reads before the t+1 overwrite). Stage latency hides under ds_read+MFMA of t.
#define BM 128
#define BN 128
#define BK 32
#define NT (IN_DIM / BK)      // 36 K-tiles

__global__ __launch_bounds__(256) void k_gemm(const unsigned short* __restrict__ A,
                                              const unsigned short* __restrict__ Bw,
                                              const float* __restrict__ bias,
                                              const float* __restrict__ qp,
                                              float* __restrict__ C) {
    __shared__ __align__(16) unsigned short As[2 * BM * BK];   // 2 x 8 KB
    __shared__ __align__(16) unsigned short Bs[2 * BN * BK];   // 2 x 8 KB
    const int tid = threadIdx.x;
    // XCD-aware remap: 2304 blocks, 8 XCDs (round-robin by linear id).
    const int lid = blockIdx.x;
    const int xcd = lid & 7;
    const int kk  = lid >> 3;            // 0..287
    const int bml = kk / 9;              // 0..31
    const int bn  = kk - bml * 9;        // 0..8
    const int bm  = xcd * 32 + bml;      // 0..255
    const int K = IN_DIM, N = OUT_DIM;

    // Staging: 512 x 16B segments per tile; thread t takes segments t and t+256.
    const int r0 = tid >> 2;
    const int c0 = (tid & 3) * 8;
    const unsigned short* ga0 = A  + (size_t)(bm * BM + r0) * K + c0;
    const unsigned short* ga1 = ga0 + (size_t)64 * K;
    const unsigned short* gb0 = Bw + (size_t)(bn * BN + r0) * K + c0;
    const unsigned short* gb1 = gb0 + (size_t)64 * K;

    f32x4 acc[4][4];
    #pragma unroll
    for (int mi = 0; mi < 4; mi++)
        #pragma unroll
        for (int ni = 0; ni < 4; ni++)
            acc[mi][ni] = (f32x4)0.0f;

    const int lane = tid & 63, wv = tid >> 6;
    const int wm = (wv & 1) * 64;          // wave m-origin within block tile
    const int wn = (wv >> 1) * 64;         // wave n-origin
    const int l16 = lane & 15, l4 = lane >> 4;
    const int afo = (wm + l16) * 4 + l4;   // A frag offset (16B units within a buf)
    const int bfo = (wn + l16) * 4 + l4;

    // ---- prologue: stage tile 0 into buffer 0 ----
    __builtin_amdgcn_global_load_lds(
        (const __attribute__((address_space(1))) unsigned int*)ga0,
        (__attribute__((address_space(3))) unsigned int*)(As + tid * 8), 16, 0, 0);
    __builtin_amdgcn_global_load_lds(
        (const __attribute__((address_space(1))) unsigned int*)ga1,
        (__attribute__((address_space(3))) unsigned int*)(As + tid * 8 + 2048), 16, 0, 0);
    __builtin_amdgcn_global_load_lds(
        (const __attribute__((address_space(1))) unsigned int*)gb0,
        (__attribute__((address_space(3))) unsigned int*)(Bs + tid * 8), 16, 0, 0);
    __builtin_amdgcn_global_load_lds(
        (const __attribute__((address_space(1))) unsigned int*)gb1,
        (__attribute__((address_space(3))) unsigned int*)(Bs + tid * 8 + 2048), 16, 0, 0);
    __syncthreads();

    for (int t = 0; t < NT; ++t) {
        const int cur = t & 1;
        const int nxt = cur ^ 1;

        // ---- STAGE(t+1): issue before compute; lands while MFMA(t) runs ----
        if (t + 1 < NT) {
            const int kc = (t + 1) * BK;
            __builtin_amdgcn_global_load_lds(
                (const __attribute__((address_space(1))) unsigned int*)(ga0 + kc),
                (__attribute__((address_space(3))) unsigned int*)(As + nxt * 4096 + tid * 8),
                16, 0, 0);
            __builtin_amdgcn_global_load_lds(
                (const __attribute__((address_space(1))) unsigned int*)(ga1 + kc),
                (__attribute__((address_space(3))) unsigned int*)(As + nxt * 4096 + tid * 8 + 2048),
                16, 0, 0);
            __builtin_amdgcn_global_load_lds(
                (const __attribute__((address_space(1))) unsigned int*)(gb0 + kc),
                (__attribute__((address_space(3))) unsigned int*)(Bs + nxt * 4096 + tid * 8),
                16, 0, 0);
            __builtin_amdgcn_global_load_lds(
                (const __attribute__((address_space(1))) unsigned int*)(gb1 + kc),
                (__attribute__((address_space(3))) unsigned int*)(Bs + nxt * 4096 + tid * 8 + 2048),
                16, 0, 0);
        }

        // ---- compute tile t from buffer cur ----
        const bf16x8* Asv = (const bf16x8*)(As + cur * 4096);
        const bf16x8* Bsv = (const bf16x8*)(Bs + cur * 4096);
        bf16x8 af[4], bf[4];
        #pragma unroll
        for (int mi = 0; mi < 4; mi++) af[mi] = Asv[afo + mi * 64];
        #pragma unroll
        for (int ni = 0; ni < 4; ni++) bf[ni] = Bsv[bfo + ni * 64];
        #pragma unroll
        for (int mi = 0; mi < 4; mi++)
            #pragma unroll
            for (int ni = 0; ni < 4; ni++)
                acc[mi][ni] = __builtin_amdgcn_mfma_f32_16x16x32_bf16(
                    af[mi], bf[ni], acc[mi][ni], 0, 0, 0);

        __syncthreads();   // vmcnt(0): stage(t+1) landed; barrier: cur reads done
    }

    const float qs = qp[0];
    #pragma unroll
    for (int mi = 0; mi < 4; mi++) {
        int row0 = bm * BM + wm + mi * 16 + l4 * 4;
        #pragma unroll
        for (int ni = 0; ni < 4; ni++) {
            int col = bn * BN + wn + ni * 16 + l16;
            float bv = bias[col];
            #pragma unroll
            for (int r = 0; r < 4; r++)
                C[(size_t)(row0 + r) * N + col] = acc[mi][ni][r] * qs + bv;
        }
    }
}

extern "C" void kernel_launch(void* const* d_in, const int* in_sizes, int n_in,
                              void* d_out, int out_size, void* d_ws, size_t ws_size,
                              hipStream_t stream) {
    const float* x      = (const float*)d_in[0];
    const float* qw     = (const float*)d_in[1];
    const float* rw     = (const float*)d_in[2];
    const float* lw     = (const float*)d_in[3];
    const float* bias   = (const float*)d_in[4];
    const float* scales = (const float*)d_in[5];

    char* ws = (char*)d_ws;
    // Workspace layout (all 16B aligned): total ~74.6 MiB
    unsigned short* xq = (unsigned short*)ws;                          // 75,497,472 B
    unsigned short* wc = (unsigned short*)(ws + 75497472);             //  2,654,208 B
    float* partials    = (float*)(ws + 75497472 + 2654208);            //     16,384 B
    float* qp          = (float*)(ws + 75497472 + 2654208 + 16384);    //         64 B
    float* rs          = (float*)(ws + 75497472 + 2654208 + 16384 + 64);        // 4608 B
    float* comb        = (float*)(ws + 75497472 + 2654208 + 16384 + 64 + 4608); // 4608 B

    k_wprep   <<<(OUT_DIM * IN_DIM) / 256, 256, 0, stream>>>(qw, rw, lw, scales, wc, rs);
    k_minmax  <<<RED_BLOCKS, 256, 0, stream>>>(x, rs, partials);
    k_finalize<<<1,          256, 0, stream>>>(partials, scales, qp, comb);
    k_quant   <<<QBLOCKS,    256, 0, stream>>>(x, comb, qp, xq);

    k_gemm<<<2304, 256, 0, stream>>>(xq, wc, bias, qp, (float*)d_out);
}

// Round 6
// 418.097 us; speedup vs baseline: 1.2470x; 1.0479x over previous
//
#include <hip/hip_runtime.h>
#include <hip/hip_bf16.h>
#include <stdint.h>

// Problem constants (from reference setup_inputs)
#define M_DIM   32768        // B*S = 32*1024
#define IN_DIM  1152
#define OUT_DIM 1152
#define R_DIM   64
#define QMAXF   255.0f

#define MM_BLOCKS 2048                       // minmax-role blocks
#define WP_BLOCKS (OUT_DIM * IN_DIM / 256)   // 5184 weight-fold blocks
#define QBLOCKS   4096

typedef float  f32x4  __attribute__((ext_vector_type(4)));
typedef __bf16 bf16x8 __attribute__((ext_vector_type(8)));

// RNE float -> bf16 bits (finite inputs only)
static __device__ __forceinline__ unsigned short f2bf(float f) {
    unsigned int u = __float_as_uint(f);
    unsigned int r = (u + 0x7fffu + ((u >> 16) & 1u)) >> 16;
    return (unsigned short)r;
}

// ---------------- Pass 0: role-split prep kernel --------------------------------
// Blocks [0, MM_BLOCKS):       global min/max of x * (1/scales) -> partials
// Blocks [MM_BLOCKS, +WP_BLOCKS): Wc[o][i] = qw[o][i] + sum_r lw[o][r]*rw[r][i] (bf16)
//                                 + rs[c] = 1/scales[c] (for k_quantf)
// Roles are independent (weights vs activations) -> no intra-kernel ordering.
__global__ __launch_bounds__(256) void k_prep(const float* __restrict__ x,
                                              const float* __restrict__ scales,
                                              const float* __restrict__ qw,
                                              const float* __restrict__ rw,
                                              const float* __restrict__ lw,
                                              unsigned short* __restrict__ wc,
                                              float* __restrict__ rs,
                                              float* __restrict__ partials) {
    __shared__ __align__(16) float srs[IN_DIM];   // minmax role: per-block recip table
    __shared__ float smn[4], smx[4];

    if (blockIdx.x < MM_BLOCKS) {
        // ---- minmax role ----
        for (int c = threadIdx.x; c < IN_DIM; c += 256)
            srs[c] = 1.0f / scales[c];
        __syncthreads();

        const int n4 = (M_DIM * IN_DIM) / 4;      // 9,437,184 float4s; 2048*256*18
        int tid = blockIdx.x * 256 + threadIdx.x;
        const int stride = MM_BLOCKS * 256;
        float mn = 3.4e38f, mx = -3.4e38f;
        for (int i4 = tid; i4 < n4; i4 += stride) {
            int i = i4 * 4;
            float4 xv = *(const float4*)(x + i);
            int c = i % IN_DIM;                   // IN_DIM % 4 == 0 -> 16B aligned
            float4 sv = *(const float4*)(&srs[c]);
            float a0 = xv.x * sv.x, a1 = xv.y * sv.y;
            float a2 = xv.z * sv.z, a3 = xv.w * sv.w;
            mn = fminf(mn, fminf(fminf(a0, a1), fminf(a2, a3)));
            mx = fmaxf(mx, fmaxf(fmaxf(a0, a1), fmaxf(a2, a3)));
        }
        #pragma unroll
        for (int off = 32; off > 0; off >>= 1) {
            mn = fminf(mn, __shfl_down(mn, off));
            mx = fmaxf(mx, __shfl_down(mx, off));
        }
        int lane = threadIdx.x & 63, wv = threadIdx.x >> 6;
        if (lane == 0) { smn[wv] = mn; smx[wv] = mx; }
        __syncthreads();
        if (threadIdx.x == 0) {
            float bmn = fminf(fminf(smn[0], smn[1]), fminf(smn[2], smn[3]));
            float bmx = fmaxf(fmaxf(smx[0], smx[1]), fmaxf(smx[2], smx[3]));
            partials[blockIdx.x * 2]     = bmn;
            partials[blockIdx.x * 2 + 1] = bmx;
        }
    } else {
        // ---- weight-fold role ----
        int idx = (blockIdx.x - MM_BLOCKS) * 256 + threadIdx.x;  // over OUT*IN, exact
        if (idx < IN_DIM) rs[idx] = 1.0f / scales[idx];
        int o = idx / IN_DIM;
        int i = idx - o * IN_DIM;
        float acc = qw[idx];
        #pragma unroll 8
        for (int r = 0; r < R_DIM; r++)
            acc += lw[o * R_DIM + r] * rw[r * IN_DIM + i];
        wc[idx] = f2bf(acc);
    }
}

// ---------------- Pass 1: fused finalize + quantize ------------------------------
// Every block reduces the 2048 partial pairs (16 KB, L2-hit) -> qs, zp, lo, hi, rqs
// (deterministic, identical in all blocks). Block 0 publishes qp[0]=qs for k_gemm.
// Then stream-quantize: q - zp = clamp(rint((x*rs)*rqs), -zp, 255-zp), exact bf16.
__global__ __launch_bounds__(256) void k_quantf(const float* __restrict__ x,
                                                const float* __restrict__ rs,
                                                const float* __restrict__ partials,
                                                float* __restrict__ qp,
                                                unsigned short* __restrict__ xq) {
    __shared__ float smn[4], smx[4];
    __shared__ float s_lo, s_hi, s_rqs;

    float mn = 3.4e38f, mx = -3.4e38f;
    for (int i = threadIdx.x; i < MM_BLOCKS; i += 256) {   // 8 iters
        mn = fminf(mn, partials[i * 2]);
        mx = fmaxf(mx, partials[i * 2 + 1]);
    }
    #pragma unroll
    for (int off = 32; off > 0; off >>= 1) {
        mn = fminf(mn, __shfl_down(mn, off));
        mx = fmaxf(mx, __shfl_down(mx, off));
    }
    int lane = threadIdx.x & 63, wv = threadIdx.x >> 6;
    if (lane == 0) { smn[wv] = mn; smx[wv] = mx; }
    __syncthreads();
    if (threadIdx.x == 0) {
        float bmn = fminf(fminf(smn[0], smn[1]), fminf(smn[2], smn[3]));
        float bmx = fmaxf(fmaxf(smx[0], smx[1]), fmaxf(smx[2], smx[3]));
        float qs = (bmx - bmn) / QMAXF;
        float zp = rintf(-bmn / qs);
        s_lo  = -zp;               // clamp lo for (q - zp)
        s_hi  = QMAXF - zp;        // clamp hi for (q - zp)
        s_rqs = 1.0f / qs;
        if (blockIdx.x == 0) qp[0] = qs;       // for gemm epilogue (stream-ordered)
    }
    __syncthreads();
    const float lo = s_lo, hi = s_hi, rqs = s_rqs;

    const int n4 = (M_DIM * IN_DIM) / 4;
    int tid = blockIdx.x * 256 + threadIdx.x;
    const int stride = QBLOCKS * 256;
    for (int i4 = tid; i4 < n4; i4 += stride) {
        int i = i4 * 4;
        float4 xv = *(const float4*)(x + i);
        int c = i % IN_DIM;
        float4 sv = *(const float4*)(rs + c);
        float a[4] = { (xv.x * sv.x) * rqs, (xv.y * sv.y) * rqs,
                       (xv.z * sv.z) * rqs, (xv.w * sv.w) * rqs };
        ushort4 o;
        unsigned short* op = (unsigned short*)&o;
        #pragma unroll
        for (int j = 0; j < 4; j++) {
            float q = rintf(a[j]);
            q = fminf(fmaxf(q, lo), hi);
            op[j] = f2bf(q);                  // integer in [-255,255]: exact in bf16
        }
        *(ushort4*)(xq + i) = o;
    }
}

// ---------------- Pass 2: GEMM  C = qs * (A @ Wc^T) + bias -----------------------
// A: [M][K] bf16 (q - zp), Wc: [N][K] bf16, C: [M][N] fp32
// R0-proven structure: single-buffer, BK=32, dim3(256,9) grid (xq+wc are
// L3-resident, so no XCD swizzle needed; measured fastest at 131.8 us).
#define BM 128
#define BN 128
#define BK 32

__global__ __launch_bounds__(256) void k_gemm(const unsigned short* __restrict__ A,
                                              const unsigned short* __restrict__ Bw,
                                              const float* __restrict__ bias,
                                              const float* __restrict__ qp,
                                              float* __restrict__ C) {
    __shared__ __align__(16) unsigned short As[BM * BK];   // 8 KB
    __shared__ __align__(16) unsigned short Bs[BN * BK];   // 8 KB
    const int tid = threadIdx.x;
    const int bm = blockIdx.x, bn = blockIdx.y;
    const int K = IN_DIM, N = OUT_DIM;

    // Staging: 512 segments of 16B per tile; thread t takes segments t and t+256.
    const int r0 = tid >> 2;
    const int c0 = (tid & 3) * 8;
    const unsigned short* ga0 = A  + (size_t)(bm * BM + r0) * K + c0;
    const unsigned short* ga1 = ga0 + (size_t)64 * K;
    const unsigned short* gb0 = Bw + (size_t)(bn * BN + r0) * K + c0;
    const unsigned short* gb1 = gb0 + (size_t)64 * K;
    unsigned short* lA0 = As + tid * 8;
    unsigned short* lA1 = As + tid * 8 + 2048;
    unsigned short* lB0 = Bs + tid * 8;
    unsigned short* lB1 = Bs + tid * 8 + 2048;

    f32x4 acc[4][4];
    #pragma unroll
    for (int mi = 0; mi < 4; mi++)
        #pragma unroll
        for (int ni = 0; ni < 4; ni++)
            acc[mi][ni] = (f32x4)0.0f;

    const int lane = tid & 63, wv = tid >> 6;
    const int wm = (wv & 1) * 64;          // wave m-origin within block tile
    const int wn = (wv >> 1) * 64;         // wave n-origin
    const int l16 = lane & 15, l4 = lane >> 4;
    const bf16x8* Asv = (const bf16x8*)As; // row stride = 4 (in 16B units)
    const bf16x8* Bsv = (const bf16x8*)Bs;
    const int afo = (wm + l16) * 4 + l4;   // A[m=lane&15][k=(lane>>4)*8+j]
    const int bfo = (wn + l16) * 4 + l4;   // B[k][n=lane&15] from Wc[n][k]

    for (int k0 = 0; k0 < K; k0 += BK) {
        __builtin_amdgcn_global_load_lds(
            (const __attribute__((address_space(1))) unsigned int*)(ga0 + k0),
            (__attribute__((address_space(3))) unsigned int*)lA0, 16, 0, 0);
        __builtin_amdgcn_global_load_lds(
            (const __attribute__((address_space(1))) unsigned int*)(ga1 + k0),
            (__attribute__((address_space(3))) unsigned int*)lA1, 16, 0, 0);
        __builtin_amdgcn_global_load_lds(
            (const __attribute__((address_space(1))) unsigned int*)(gb0 + k0),
            (__attribute__((address_space(3))) unsigned int*)lB0, 16, 0, 0);
        __builtin_amdgcn_global_load_lds(
            (const __attribute__((address_space(1))) unsigned int*)(gb1 + k0),
            (__attribute__((address_space(3))) unsigned int*)lB1, 16, 0, 0);
        __syncthreads();                   // drains vmcnt: LDS tiles valid

        bf16x8 af[4], bf[4];
        #pragma unroll
        for (int mi = 0; mi < 4; mi++) af[mi] = Asv[afo + mi * 64];
        #pragma unroll
        for (int ni = 0; ni < 4; ni++) bf[ni] = Bsv[bfo + ni * 64];
        #pragma unroll
        for (int mi = 0; mi < 4; mi++)
            #pragma unroll
            for (int ni = 0; ni < 4; ni++)
                acc[mi][ni] = __builtin_amdgcn_mfma_f32_16x16x32_bf16(
                    af[mi], bf[ni], acc[mi][ni], 0, 0, 0);
        __syncthreads();                   // LDS reads done before next overwrite
    }

    const float qs = qp[0];
    #pragma unroll
    for (int mi = 0; mi < 4; mi++) {
        int row0 = bm * BM + wm + mi * 16 + l4 * 4;
        #pragma unroll
        for (int ni = 0; ni < 4; ni++) {
            int col = bn * BN + wn + ni * 16 + l16;
            float bv = bias[col];
            #pragma unroll
            for (int r = 0; r < 4; r++)
                C[(size_t)(row0 + r) * N + col] = acc[mi][ni][r] * qs + bv;
        }
    }
}

extern "C" void kernel_launch(void* const* d_in, const int* in_sizes, int n_in,
                              void* d_out, int out_size, void* d_ws, size_t ws_size,
                              hipStream_t stream) {
    const float* x      = (const float*)d_in[0];
    const float* qw     = (const float*)d_in[1];
    const float* rw     = (const float*)d_in[2];
    const float* lw     = (const float*)d_in[3];
    const float* bias   = (const float*)d_in[4];
    const float* scales = (const float*)d_in[5];

    char* ws = (char*)d_ws;
    // Workspace layout (all 16B aligned): total ~74.6 MiB
    unsigned short* xq = (unsigned short*)ws;                          // 75,497,472 B
    unsigned short* wc = (unsigned short*)(ws + 75497472);             //  2,654,208 B
    float* partials    = (float*)(ws + 75497472 + 2654208);            //     16,384 B
    float* qp          = (float*)(ws + 75497472 + 2654208 + 16384);    //         64 B
    float* rs          = (float*)(ws + 75497472 + 2654208 + 16384 + 64);        // 4608 B

    k_prep  <<<MM_BLOCKS + WP_BLOCKS, 256, 0, stream>>>(x, scales, qw, rw, lw,
                                                        wc, rs, partials);
    k_quantf<<<QBLOCKS, 256, 0, stream>>>(x, rs, partials, qp, xq);

    dim3 grid(M_DIM / BM, OUT_DIM / BN);   // 256 x 9
    k_gemm<<<grid, 256, 0, stream>>>(xq, wc, bias, qp, (float*)d_out);
}